// Round 10
// baseline (134.249 us; speedup 1.0000x reference)
//
#include <hip/hip_runtime.h>

// CTC loss forward, f64 prob-domain with power-of-2 rescaling.
// v11: v5 skeleton (fwd/bwd separate blocks, 4 waves x 4 states, ghost-zone
// halo, chunked rescale) + HALF-CHUNK REGISTER BURSTS sized to fit VGPR.
// Failure taxonomy from v7-v10: compiler SINKS free loads (v7), SPILLS
// pinned pipelines that exceed the 256-VGPR wave cap (v8: 192 floats + 68
// base ~ 260 -> scratch), COLLAPSES rotating slots (v9), and spills
// asm-output arrays (v10). The untested point: pinned groups that FIT.
//  (a) two groups GA/GB of 8 pairs x 6 floats (96 total; ~170 VGPR incl.
//      base) -- burst issued ~8 pairs (~1000 cy) before consumption;
//  (b) __builtin_amdgcn_sched_barrier(0) after each burst: in straight-line
//      unrolled code this stops scheduler sinking; no asm, no early-clobber;
//  (c) blank column read from GLOBAL uniform address inside the burst
//      (bytes == DMA'd LDS copy, v9-verified) -- off the LDS pipe;
//  (d) bwd cc column via f32 DPP of ca (v9-verified bit-identical);
//  (e) combine folded: last-finisher atomic (v8-proven).
// f64 op order per state IDENTICAL to v5 -> absmax must stay 0.0.
// ws per b (doubles, stride 1028): [0..512] alphaF, [513] toteF,
// [514..1026] betaB, [1027] toteB; int flags at double-offset 64*1028.

#define Bc 64
#define Tc 1024
#define Cc 128
#define Lc 256
#define Sc 513
#define BLANKc 127
#define CHUNK 32
#define NW 4
#define PADS 64
#define WSSTRIDE 1028
#define FLAGS_OFF (Bc * WSSTRIDE)

constexpr float EPSF = 1e-7f;

#define DPPMAXI(x, ctrl) max(x, __builtin_amdgcn_update_dpp( \
    0, x, ctrl, 0xf, 0xf, true))

__device__ __forceinline__ double dpp_wave_shr1_f64(double x) {
    // lane l <- lane l-1; lane 0 <- 0 (bound_ctrl)
    union { double d; int i[2]; } u, r;
    u.d = x;
    r.i[0] = __builtin_amdgcn_update_dpp(0, u.i[0], 0x138, 0xf, 0xf, true);
    r.i[1] = __builtin_amdgcn_update_dpp(0, u.i[1], 0x138, 0xf, 0xf, true);
    return r.d;
}
__device__ __forceinline__ double dpp_wave_shl1_f64(double x) {
    // lane l <- lane l+1; lane 63 <- 0 (bound_ctrl)
    union { double d; int i[2]; } u, r;
    u.d = x;
    r.i[0] = __builtin_amdgcn_update_dpp(0, u.i[0], 0x130, 0xf, 0xf, true);
    r.i[1] = __builtin_amdgcn_update_dpp(0, u.i[1], 0x130, 0xf, 0xf, true);
    return r.d;
}
__device__ __forceinline__ float dpp_wave_shl1_f32(float x) {
    union { float f; int i; } u, r;
    u.f = x;
    r.i = __builtin_amdgcn_update_dpp(0, u.i, 0x130, 0xf, 0xf, true);
    return r.f;
}

// fwd burst: G[p] <- pair p of this half (rows 2p, 2p+1 rel. to base).
// blank from GLOBAL (gbase = global row base + BLANKc), labels from LDS.
#define BURSTF(G, base, gbase) do {                                  \
    _Pragma("unroll")                                                \
    for (int p = 0; p < 8; ++p) {                                    \
        const float* rp = (base) + 2 * p * Cc;                       \
        const float* gp = (gbase) + 2 * p * Cc;                      \
        G[p][0] = gp[0];      G[p][1] = gp[Cc];                      \
        G[p][2] = rp[ca];     G[p][3] = rp[ca + Cc];                 \
        G[p][4] = rp[cb];     G[p][5] = rp[cb + Cc];                 \
    }                                                                \
    __builtin_amdgcn_sched_barrier(0);                               \
} while (0)

// bwd burst: G[i] <- pair (hi - i), i=0..7 (consume order = descending).
#define BURSTB(G, base, gbase, hi) do {                              \
    _Pragma("unroll")                                                \
    for (int i = 0; i < 8; ++i) {                                    \
        const int r = 2 * ((hi) - i);                                \
        const float* rp = (base) + r * Cc;                           \
        const float* gp = (gbase) + r * Cc;                          \
        G[i][0] = gp[0];      G[i][1] = gp[Cc];                      \
        G[i][2] = rp[ca];     G[i][3] = rp[ca + Cc];                 \
        G[i][4] = rp[cb];     G[i][5] = rp[cb + Cc];                 \
    }                                                                \
    __builtin_amdgcn_sched_barrier(0);                               \
} while (0)

__global__ __launch_bounds__(256, 1) void ctc_fb_kernel(
    const int* __restrict__ y_true,        // [B, L]
    const float* __restrict__ y_pred,      // [B, T, C]
    const int* __restrict__ label_length,  // [B, 1]
    double* __restrict__ ws,
    float* __restrict__ out)               // [B, 1]
{
    const int bb = blockIdx.x;
    const int b = bb >> 1;
    const bool isF = !(bb & 1);
    const int tid = (int)threadIdx.x;
    const int wl = tid >> 6;               // wave 0..3
    const int lane = tid & 63;

    __shared__ float bufs[3][CHUNK * Cc];  // 3 x 16 KB staged y_pred rows
    __shared__ double ash[Sc];             // owned-alpha/beta exchange
    __shared__ int em[NW];                 // per-wave masked exponent max
    __shared__ int amlast;

    const int lab_len = label_length[b];
    const float* yp = y_pred + (size_t)b * Tc * Cc;
    const int* lab = y_true + b * Lc;
    double* wsb = ws + (size_t)b * WSSTRIDE;

    // ---- region geometry (starts EVEN). fwd pads BELOW owned, bwd ABOVE.
    const int start = isF ? ((wl == 0) ? 0 : (128 * wl - PADS)) : (128 * wl);
    const int own_s = 128 * wl;
    const int own_e = (wl == NW - 1) ? Sc : (128 * (wl + 1));
    const int s0 = start + 4 * lane;       // even; lane holds s0..s0+3

    // ---- per-lane static metadata ----
    const int li0 = s0 >> 1;               // label idx of state s0+1
    const int li0c = min(li0, Lc - 1);
    const int li1c = min(li0 + 1, Lc - 1);
    const int li2c = min(li0 + 2, Lc - 1);
    const int ca = lab[li0c], cb = lab[li1c], cc = lab[li2c];
    const double sm_a = (li0 > 0 && ca != BLANKc && ca != lab[li0c - 1]) ? 1.0 : 0.0;
    const double sm_b = (cb != BLANKc && cb != ca) ? 1.0 : 0.0;
    const double sm_c = (cc != BLANKc && cc != cb) ? 1.0 : 0.0;

    const int S2 = 2 * lab_len + 1;
    const bool ow0 = (s0     >= own_s) && (s0     < own_e);
    const bool ow1 = (s0 + 1 >= own_s) && (s0 + 1 < own_e);
    const bool ow2 = (s0 + 2 >= own_s) && (s0 + 2 < own_e);
    const bool ow3 = (s0 + 3 >= own_s) && (s0 + 3 < own_e);
    const int om0 = (ow0 && s0     < S2) ? -1 : 0;
    const int om1 = (ow1 && s0 + 1 < S2) ? -1 : 0;
    const int om2 = (ow2 && s0 + 2 < S2) ? -1 : 0;
    const int om3 = (ow3 && s0 + 3 < S2) ? -1 : 0;

    // ---- staging: each wave DMAs its quarter (4 KB) of a 16 KB chunk ----
    auto stage = [&](int c, float* dst) {
        const float* g = yp + (size_t)c * (CHUNK * Cc) + lane * 4;
        #pragma unroll
        for (int q = 0; q < 4; ++q) {
            const int i = wl * 4 + q;
            __builtin_amdgcn_global_load_lds(
                (const __attribute__((address_space(1))) void*)(g + i * 256),
                (__attribute__((address_space(3))) void*)(dst + i * 256),
                16, 0, 0);
        }
    };

    // ---- two half-chunk register groups (96 floats; fits VGPR cap) ----
    float GA[8][6], GB[8][6];

    if (isF) {
        // =================== FORWARD: rows 0 .. 511 ===================
        double a0 = 0, a1 = 0, a2 = 0, a3 = 0, n3 = 0;
        int tote = 0;
        double Eb, Ea, Ec, Ob, Oa, Oc;

        auto stepE = [&]() {
            const double t3 = __fma_rn(sm_b, a1, a3 + a2);
            const double t2 = a2 + a1;
            const double t1 = __fma_rn(sm_a, n3, a1 + a0);
            const double t0 = a0 + n3;
            a3 = t3 * Ec;
            n3 = dpp_wave_shr1_f64(a3);
            a2 = t2 * Eb; a1 = t1 * Ea; a0 = t0 * Eb;
        };
        auto stepO = [&]() {
            const double t3 = __fma_rn(sm_b, a1, a3 + a2);
            const double t2 = a2 + a1;
            const double t1 = __fma_rn(sm_a, n3, a1 + a0);
            const double t0 = a0 + n3;
            a3 = t3 * Oc;
            n3 = dpp_wave_shr1_f64(a3);
            a2 = t2 * Ob; a1 = t1 * Oa; a0 = t0 * Ob;
        };
        auto pairF = [&](const float* s) {
            Eb = (double)(s[0] + EPSF); Ea = (double)(s[2] + EPSF);
            Ec = (double)(s[4] + EPSF);
            stepE();
            Ob = (double)(s[1] + EPSF); Oa = (double)(s[3] + EPSF);
            Oc = (double)(s[5] + EPSF);
            stepO();
        };
        auto syncex = [&](int sk) {
            int e =        om0 & (__double2hiint(a0) >> 20);
            e = max(e, om1 & (__double2hiint(a1) >> 20));
            e = max(e, om2 & (__double2hiint(a2) >> 20));
            e = max(e, om3 & (__double2hiint(a3) >> 20));
            e = DPPMAXI(e, 0x111); e = DPPMAXI(e, 0x112);
            e = DPPMAXI(e, 0x114); e = DPPMAXI(e, 0x118);
            e = DPPMAXI(e, 0x142); e = DPPMAXI(e, 0x143);
            if (lane == 63) em[wl] = e;
            if (ow0) ash[s0]     = a0;
            if (ow1) ash[s0 + 1] = a1;
            if (ow2) ash[s0 + 2] = a2;
            if (ow3) ash[s0 + 3] = a3;
            __syncthreads();               // barrier 1 (drains lgkm + vm)
            const int eg = max(max(em[0], em[1]), max(em[2], em[3]));
            const int sexp = min(max(2046 - eg, 1), 2045);
            const double sc = __hiloint2double(sexp << 20, 0);
            tote += 1023 - sexp;
            if (wl > 0 && lane < (PADS / 4)) {   // refresh pad from below-owner
                a0 = ash[s0];     a1 = ash[s0 + 1];
                a2 = ash[s0 + 2]; a3 = ash[s0 + 3];
            }
            a0 *= sc; a1 *= sc; a2 *= sc; a3 *= sc;
            n3 = dpp_wave_shr1_f64(a3);
            __syncthreads();               // barrier 2 (ash/em reuse safe)
            if (sk <= 15) stage(sk, bufs[sk % 3]);  // DMA after barrier
        };

        // ---- prologue ----
        stage(0, bufs[0]); stage(1, bufs[1]); stage(2, bufs[2]);
        __syncthreads();

        // chunk 0: burst both halves, init from GA[0], lone stepO, pairs
        BURSTF(GA, bufs[0], yp + BLANKc);
        BURSTF(GB, bufs[0] + 16 * Cc, yp + (size_t)16 * Cc + BLANKc);
        if (wl == 0 && lane == 0) {
            a0 = (double)(GA[0][0] + EPSF);                      // s=0
            if (lab_len > 0) a1 = (double)(GA[0][2] + EPSF);     // s=1
        }
        Ob = (double)(GA[0][1] + EPSF);
        Oa = (double)(GA[0][3] + EPSF);
        Oc = (double)(GA[0][5] + EPSF);
        stepO();                           // lone step t=1
        #pragma unroll
        for (int p = 1; p < 8; ++p) pairF(GA[p]);
        BURSTF(GA, bufs[1], yp + (size_t)CHUNK * Cc + BLANKc);   // chunk 1 lo
        #pragma unroll
        for (int p = 0; p < 8; ++p) pairF(GB[p]);

        // chunks 1..15 (rows 32..511)
        for (int k = 1; k < 16; ++k) {
            syncex(k + 2);
            const float* rb = bufs[k % 3];
            const float* gB = yp + (size_t)k * (CHUNK * Cc) + BLANKc;
            BURSTF(GB, rb + 16 * Cc, gB + 16 * Cc);     // this chunk hi
            #pragma unroll
            for (int p = 0; p < 8; ++p) pairF(GA[p]);
            if (k < 15)
                BURSTF(GA, bufs[(k + 1) % 3],
                       yp + (size_t)(k + 1) * (CHUNK * Cc) + BLANKc);
            #pragma unroll
            for (int p = 0; p < 8; ++p) pairF(GB[p]);
        }
        // publish alpha_511 (pre-rescale) + toteF
        if (ow0) wsb[s0]     = a0;
        if (ow1) wsb[s0 + 1] = a1;
        if (ow2) wsb[s0 + 2] = a2;
        if (ow3) wsb[s0 + 3] = a3;
        if (tid == 0) wsb[513] = (double)tote;
    } else {
        // =================== BACKWARD: rows 1023 .. 512 ===================
        double b0 = 0, b1 = 0, b2 = 0, b3 = 0, n0 = 0, n1 = 0;
        int tote = 0;
        double Eb, Ea, Ec, Ed, Ob, Oa, Oc, Od;

        auto stepBE = [&]() {
            const double x1 = Ea * b1, x2 = Eb * b2, x3 = Ec * b3, z = Ed * n1;
            const double r0 = __fma_rn(Eb, b0, x1);
            const double r1 = __fma_rn(sm_b, x3, x1 + x2);
            const double r2 = x2 + x3;
            const double r3 = __fma_rn(sm_c, z, __fma_rn(Eb, n0, x3));
            b0 = r0; b1 = r1; b2 = r2; b3 = r3;
            n0 = dpp_wave_shl1_f64(b0);
            n1 = dpp_wave_shl1_f64(b1);
        };
        auto stepBO = [&]() {
            const double x1 = Oa * b1, x2 = Ob * b2, x3 = Oc * b3, z = Od * n1;
            const double r0 = __fma_rn(Ob, b0, x1);
            const double r1 = __fma_rn(sm_b, x3, x1 + x2);
            const double r2 = x2 + x3;
            const double r3 = __fma_rn(sm_c, z, __fma_rn(Ob, n0, x3));
            b0 = r0; b1 = r1; b2 = r2; b3 = r3;
            n0 = dpp_wave_shl1_f64(b0);
            n1 = dpp_wave_shl1_f64(b1);
        };
        auto pairB = [&](const float* s) {
            Ob = (double)(s[1] + EPSF); Oa = (double)(s[3] + EPSF);
            Oc = (double)(s[5] + EPSF);
            Od = (double)(dpp_wave_shl1_f32(s[3]) + EPSF);   // cc = nbr ca
            stepBO();
            Eb = (double)(s[0] + EPSF); Ea = (double)(s[2] + EPSF);
            Ec = (double)(s[4] + EPSF);
            Ed = (double)(dpp_wave_shl1_f32(s[2]) + EPSF);
            stepBE();
        };
        auto syncex = [&](int sk) {
            int e =        om0 & (__double2hiint(b0) >> 20);
            e = max(e, om1 & (__double2hiint(b1) >> 20));
            e = max(e, om2 & (__double2hiint(b2) >> 20));
            e = max(e, om3 & (__double2hiint(b3) >> 20));
            e = DPPMAXI(e, 0x111); e = DPPMAXI(e, 0x112);
            e = DPPMAXI(e, 0x114); e = DPPMAXI(e, 0x118);
            e = DPPMAXI(e, 0x142); e = DPPMAXI(e, 0x143);
            if (lane == 63) em[wl] = e;
            if (ow0) ash[s0]     = b0;
            if (ow1) ash[s0 + 1] = b1;
            if (ow2) ash[s0 + 2] = b2;
            if (ow3) ash[s0 + 3] = b3;
            __syncthreads();               // barrier 1
            const int eg = max(max(em[0], em[1]), max(em[2], em[3]));
            const int sexp = min(max(2046 - eg, 1), 2045);
            const double sc = __hiloint2double(sexp << 20, 0);
            tote += 1023 - sexp;
            // refresh pad above from owner; zero beyond S space
            if (s0     >= own_e) b0 = (s0     < Sc) ? ash[s0]     : 0.0;
            if (s0 + 1 >= own_e) b1 = (s0 + 1 < Sc) ? ash[s0 + 1] : 0.0;
            if (s0 + 2 >= own_e) b2 = (s0 + 2 < Sc) ? ash[s0 + 2] : 0.0;
            if (s0 + 3 >= own_e) b3 = (s0 + 3 < Sc) ? ash[s0 + 3] : 0.0;
            b0 *= sc; b1 *= sc; b2 *= sc; b3 *= sc;
            n0 = dpp_wave_shl1_f64(b0);
            n1 = dpp_wave_shl1_f64(b1);
            __syncthreads();               // barrier 2
            if (sk >= 16) stage(sk, bufs[(31 - sk) % 3]);
        };

        // ---- prologue: chunks 31,30,29 -> bufs 0,1,2 ----
        stage(31, bufs[0]); stage(30, bufs[1]); stage(29, bufs[2]);
        __syncthreads();

        // init beta_{1023}: 1 at end states {2L, 2L-1}
        {
            const int e0 = 2 * lab_len;
            const int e1 = (lab_len > 0) ? (2 * lab_len - 1) : e0;
            b0 = (s0     == e0 || s0     == e1) ? 1.0 : 0.0;
            b1 = (s0 + 1 == e0 || s0 + 1 == e1) ? 1.0 : 0.0;
            b2 = (s0 + 2 == e0 || s0 + 2 == e1) ? 1.0 : 0.0;
            b3 = (s0 + 3 == e0 || s0 + 3 == e1) ? 1.0 : 0.0;
            n0 = dpp_wave_shl1_f64(b0);
            n1 = dpp_wave_shl1_f64(b1);
        }
        // chunk 31: GA = pairs 15..8, GB = pairs 7..0
        {
            const float* gB = yp + (size_t)31 * (CHUNK * Cc) + BLANKc;
            BURSTB(GA, bufs[0], gB, 15);
            BURSTB(GB, bufs[0], gB, 7);
            #pragma unroll
            for (int i = 0; i < 8; ++i) pairB(GA[i]);
            BURSTB(GA, bufs[1], yp + (size_t)30 * (CHUNK * Cc) + BLANKc, 15);
            #pragma unroll
            for (int i = 0; i < 8; ++i) pairB(GB[i]);
        }
        // chunks 30..16
        for (int c = 30; c >= 16; --c) {
            syncex(c - 2);
            const float* rb = bufs[(31 - c) % 3];
            const float* gB = yp + (size_t)c * (CHUNK * Cc) + BLANKc;
            BURSTB(GB, rb, gB, 7);                      // this chunk lo half
            #pragma unroll
            for (int i = 0; i < 8; ++i) pairB(GA[i]);
            if (c > 16)
                BURSTB(GA, bufs[(32 - c) % 3],
                       yp + (size_t)(c - 1) * (CHUNK * Cc) + BLANKc, 15);
            #pragma unroll
            for (int i = 0; i < 8; ++i) pairB(GB[i]);
        }
        // publish beta_511 (pre-rescale) + toteB
        if (ow0) wsb[514 + s0]     = b0;
        if (ow1) wsb[514 + s0 + 1] = b1;
        if (ow2) wsb[514 + s0 + 2] = b2;
        if (ow3) wsb[514 + s0 + 3] = b3;
        if (tid == 0) wsb[1027] = (double)tote;
    }

    // ---- folded combine: last finisher for batch b does dot + log ----
    __threadfence();                       // release our ws writes
    if (tid == 0) {
        int* flags = (int*)(ws + FLAGS_OFF);
        amlast = (atomicAdd(&flags[b], 1) == 1);
    }
    __syncthreads();
    if (amlast && tid < 64) {
        __threadfence();                   // acquire other block's writes
        const double* wf = ws + (size_t)b * WSSTRIDE;
        const double* wb = wf + 514;
        int eP = 0;                        // max biased-exponent product sum
        for (int s = tid; s < S2; s += 64) {
            const int ea = (__double2hiint(wf[s]) >> 20) & 0x7ff;
            const int eb2 = (__double2hiint(wb[s]) >> 20) & 0x7ff;
            if (ea && eb2) eP = max(eP, ea + eb2);
        }
        #pragma unroll
        for (int m = 1; m < 64; m <<= 1) eP = max(eP, __shfl_xor(eP, m));
        const int sh = 2046 - eP;
        int k1 = sh / 2;
        int k2 = sh - k1;
        k1 = min(max(k1, -1022), 1023);
        k2 = min(max(k2, -1022), 1023);
        const double scA = __hiloint2double((1023 + k1) << 20, 0);
        const double scB = __hiloint2double((1023 + k2) << 20, 0);
        double dot = 0.0;
        for (int s = tid; s < S2; s += 64)
            dot += (wf[s] * scA) * (wb[s] * scB);
        #pragma unroll
        for (int m = 1; m < 64; m <<= 1) dot += __shfl_xor(dot, m);
        if (tid == 0) {
            const double lt = wf[513] + wb[513] - (double)k1 - (double)k2;
            out[b] = (float)(-(log(dot) + lt * 0.6931471805599453));
        }
    }
}

extern "C" void kernel_launch(void* const* d_in, const int* in_sizes, int n_in,
                              void* d_out, int out_size, void* d_ws, size_t ws_size,
                              hipStream_t stream) {
    const int*   y_true       = (const int*)d_in[0];
    const float* y_pred       = (const float*)d_in[1];
    const int*   label_length = (const int*)d_in[3];
    float* out = (float*)d_out;
    double* ws = (double*)d_ws;

    hipMemsetAsync((char*)d_ws + FLAGS_OFF * sizeof(double), 0,
                   Bc * sizeof(int), stream);
    ctc_fb_kernel<<<2 * Bc, NW * 64, 0, stream>>>(y_true, y_pred,
                                                  label_length, ws, out);
}

// Round 11
// 128.294 us; speedup vs baseline: 1.0464x; 1.0464x over previous
//
#include <hip/hip_runtime.h>

// CTC loss forward, f64 prob-domain with power-of-2 rescaling.
// v12: v5 skeleton (fwd/bwd separate blocks, 4 waves x 4 states, ghost-zone
// halo, 3-slot gather pipeline, chunked rescale) + OP DELETION, not
// rescheduling (v7-v11 taxonomy: compiler sinks free loads, spills pinned
// buffers >=96 floats -- register pipelines are unhostable).
//  (a) BLANK COLUMN VIA READLANE: blank is lane-uniform, row is a
//      compile-time constant -> one coalesced global load per chunk per
//      wave (blv: lane t holds blank[row t]; 2 VGPRs, double-buffered),
//      then per pair v_readlane(blv, row) = 2-cy VALU broadcast. Zero LDS
//      ops, and Eb (3 of 5 multipliers/step) leaves the lgkm critical path.
//  (b) bwd cc = neighbor lane's ca -> f32 DPP (v9/v10-proven bit-identical).
//  Both directions: 4 LDS reads/pair (ca,cb e/o), 256 ops/chunk/block
//  (was 384 fwd / 512 bwd) ~= 72 cy/step LDS vs ~106.
//  (c) combine folded: last-finisher device-scope atomic (v8-proven).
// Same f32 bits consumed (readlane broadcasts the exact bytes), same f64
// op order per state -> absmax must stay 0.0.
// ws per b (doubles, stride 1028): [0..512] alphaF, [513] toteF,
// [514..1026] betaB, [1027] toteB; int flags at double-offset 64*1028.

#define Bc 64
#define Tc 1024
#define Cc 128
#define Lc 256
#define Sc 513
#define BLANKc 127
#define CHUNK 32
#define NW 4
#define PADS 64
#define WSSTRIDE 1028
#define FLAGS_OFF (Bc * WSSTRIDE)

constexpr float EPSF = 1e-7f;

#define DPPMAXI(x, ctrl) max(x, __builtin_amdgcn_update_dpp( \
    0, x, ctrl, 0xf, 0xf, true))

__device__ __forceinline__ double dpp_wave_shr1_f64(double x) {
    // lane l <- lane l-1; lane 0 <- 0 (bound_ctrl)
    union { double d; int i[2]; } u, r;
    u.d = x;
    r.i[0] = __builtin_amdgcn_update_dpp(0, u.i[0], 0x138, 0xf, 0xf, true);
    r.i[1] = __builtin_amdgcn_update_dpp(0, u.i[1], 0x138, 0xf, 0xf, true);
    return r.d;
}
__device__ __forceinline__ double dpp_wave_shl1_f64(double x) {
    // lane l <- lane l+1; lane 63 <- 0 (bound_ctrl)
    union { double d; int i[2]; } u, r;
    u.d = x;
    r.i[0] = __builtin_amdgcn_update_dpp(0, u.i[0], 0x130, 0xf, 0xf, true);
    r.i[1] = __builtin_amdgcn_update_dpp(0, u.i[1], 0x130, 0xf, 0xf, true);
    return r.d;
}
__device__ __forceinline__ float dpp_wave_shl1_f32(float x) {
    union { float f; int i; } u, r;
    u.f = x;
    r.i = __builtin_amdgcn_update_dpp(0, u.i, 0x130, 0xf, 0xf, true);
    return r.f;
}
__device__ __forceinline__ float rlane(float v, int l) {
    // broadcast lane l's value (compile-time l in unrolled contexts)
    return __int_as_float(__builtin_amdgcn_readlane(__float_as_int(v), l));
}

__global__ __launch_bounds__(256, 1) void ctc_fb_kernel(
    const int* __restrict__ y_true,        // [B, L]
    const float* __restrict__ y_pred,      // [B, T, C]
    const int* __restrict__ label_length,  // [B, 1]
    double* __restrict__ ws,
    float* __restrict__ out)               // [B, 1]
{
    const int bb = blockIdx.x;
    const int b = bb >> 1;
    const bool isF = !(bb & 1);
    const int tid = (int)threadIdx.x;
    const int wl = tid >> 6;               // wave 0..3
    const int lane = tid & 63;

    __shared__ float bufs[3][CHUNK * Cc];  // 3 x 16 KB staged y_pred rows
    __shared__ double ash[Sc];             // owned-alpha/beta exchange
    __shared__ int em[NW];                 // per-wave masked exponent max
    __shared__ int amlast;

    const int lab_len = label_length[b];
    const float* yp = y_pred + (size_t)b * Tc * Cc;
    const int* lab = y_true + b * Lc;
    double* wsb = ws + (size_t)b * WSSTRIDE;

    // ---- region geometry (starts EVEN). fwd pads BELOW owned, bwd ABOVE.
    const int start = isF ? ((wl == 0) ? 0 : (128 * wl - PADS)) : (128 * wl);
    const int own_s = 128 * wl;
    const int own_e = (wl == NW - 1) ? Sc : (128 * (wl + 1));
    const int s0 = start + 4 * lane;       // even; lane holds s0..s0+3

    // ---- per-lane static metadata ----
    const int li0 = s0 >> 1;               // label idx of state s0+1
    const int li0c = min(li0, Lc - 1);
    const int li1c = min(li0 + 1, Lc - 1);
    const int li2c = min(li0 + 2, Lc - 1);
    const int ca = lab[li0c], cb = lab[li1c], cc = lab[li2c];
    const double sm_a = (li0 > 0 && ca != BLANKc && ca != lab[li0c - 1]) ? 1.0 : 0.0;
    const double sm_b = (cb != BLANKc && cb != ca) ? 1.0 : 0.0;
    const double sm_c = (cc != BLANKc && cc != cb) ? 1.0 : 0.0;

    const int S2 = 2 * lab_len + 1;
    const bool ow0 = (s0     >= own_s) && (s0     < own_e);
    const bool ow1 = (s0 + 1 >= own_s) && (s0 + 1 < own_e);
    const bool ow2 = (s0 + 2 >= own_s) && (s0 + 2 < own_e);
    const bool ow3 = (s0 + 3 >= own_s) && (s0 + 3 < own_e);
    const int om0 = (ow0 && s0     < S2) ? -1 : 0;
    const int om1 = (ow1 && s0 + 1 < S2) ? -1 : 0;
    const int om2 = (ow2 && s0 + 2 < S2) ? -1 : 0;
    const int om3 = (ow3 && s0 + 3 < S2) ? -1 : 0;

    // ---- staging: each wave DMAs its quarter (4 KB) of a 16 KB chunk ----
    auto stage = [&](int c, float* dst) {
        const float* g = yp + (size_t)c * (CHUNK * Cc) + lane * 4;
        #pragma unroll
        for (int q = 0; q < 4; ++q) {
            const int i = wl * 4 + q;
            __builtin_amdgcn_global_load_lds(
                (const __attribute__((address_space(1))) void*)(g + i * 256),
                (__attribute__((address_space(3))) void*)(dst + i * 256),
                16, 0, 0);
        }
    };

    // blank-column chunk load: lane t (t=lane&31) holds blank of row t.
    auto loadblv = [&](int c) -> float {
        return yp[(size_t)c * (CHUNK * Cc) + (size_t)(lane & 31) * Cc + BLANKc];
    };

    // ---- 4 rotating pair slots, pair P in sl[P&3]; gathered 3 ahead ----
    // [0]=ca_e [1]=ca_o [2]=cb_e [3]=cb_o  (blank via readlane, cc via DPP)
    float sl[4][4];

    auto gpair = [&](const float* rowp, float* s) {
        s[0] = rowp[ca]; s[1] = rowp[ca + Cc];
        s[2] = rowp[cb]; s[3] = rowp[cb + Cc];
    };

    if (isF) {
        // =================== FORWARD: rows 0 .. 511 ===================
        double a0 = 0, a1 = 0, a2 = 0, a3 = 0, n3 = 0;
        int tote = 0;
        double Eb, Ea, Ec, Ob, Oa, Oc;
        float blvc, blvn;                  // blank regs: current / next chunk

        auto stepE = [&]() {
            const double t3 = __fma_rn(sm_b, a1, a3 + a2);
            const double t2 = a2 + a1;
            const double t1 = __fma_rn(sm_a, n3, a1 + a0);
            const double t0 = a0 + n3;
            a3 = t3 * Ec;
            n3 = dpp_wave_shr1_f64(a3);
            a2 = t2 * Eb; a1 = t1 * Ea; a0 = t0 * Eb;
        };
        auto stepO = [&]() {
            const double t3 = __fma_rn(sm_b, a1, a3 + a2);
            const double t2 = a2 + a1;
            const double t1 = __fma_rn(sm_a, n3, a1 + a0);
            const double t0 = a0 + n3;
            a3 = t3 * Oc;
            n3 = dpp_wave_shr1_f64(a3);
            a2 = t2 * Ob; a1 = t1 * Oa; a0 = t0 * Ob;
        };
        auto syncex = [&](int sk) {
            int e =        om0 & (__double2hiint(a0) >> 20);
            e = max(e, om1 & (__double2hiint(a1) >> 20));
            e = max(e, om2 & (__double2hiint(a2) >> 20));
            e = max(e, om3 & (__double2hiint(a3) >> 20));
            e = DPPMAXI(e, 0x111); e = DPPMAXI(e, 0x112);
            e = DPPMAXI(e, 0x114); e = DPPMAXI(e, 0x118);
            e = DPPMAXI(e, 0x142); e = DPPMAXI(e, 0x143);
            if (lane == 63) em[wl] = e;
            if (ow0) ash[s0]     = a0;
            if (ow1) ash[s0 + 1] = a1;
            if (ow2) ash[s0 + 2] = a2;
            if (ow3) ash[s0 + 3] = a3;
            __syncthreads();               // barrier 1 (drains lgkm + vm)
            const int eg = max(max(em[0], em[1]), max(em[2], em[3]));
            const int sexp = min(max(2046 - eg, 1), 2045);
            const double sc = __hiloint2double(sexp << 20, 0);
            tote += 1023 - sexp;
            if (wl > 0 && lane < (PADS / 4)) {   // refresh pad from below-owner
                a0 = ash[s0];     a1 = ash[s0 + 1];
                a2 = ash[s0 + 2]; a3 = ash[s0 + 3];
            }
            a0 *= sc; a1 *= sc; a2 *= sc; a3 *= sc;
            n3 = dpp_wave_shr1_f64(a3);
            __syncthreads();               // barrier 2 (ash/em reuse safe)
            if (sk <= 15) stage(sk, bufs[sk % 3]);  // DMA after barrier
        };

        // ---- prologue ----
        stage(0, bufs[0]); stage(1, bufs[1]); stage(2, bufs[2]);
        blvc = loadblv(0);                 // independent of DMA
        blvn = loadblv(1);
        __syncthreads();

        if (wl == 0 && lane == 0) {
            a0 = (double)(rlane(blvc, 0) + EPSF);                // s=0
            if (lab_len > 0) a1 = (double)(bufs[0][ca] + EPSF);  // s=1
        }
        gpair(bufs[0] + 2 * Cc, sl[1]);
        gpair(bufs[0] + 4 * Cc, sl[2]);
        gpair(bufs[0] + 6 * Cc, sl[3]);
        {   // row 1 direct -> odd set
            const float* r1 = bufs[0] + 1 * Cc;
            Ob = (double)(rlane(blvc, 1) + EPSF);
            Oa = (double)(r1[ca] + EPSF);
            Oc = (double)(r1[cb] + EPSF);
        }
        {   // expandE(pair 1): row 2
            Eb = (double)(rlane(blvc, 2) + EPSF);
            Ea = (double)(sl[1][0] + EPSF);
            Ec = (double)(sl[1][2] + EPSF);
        }
        stepO();                           // lone step t=1
        {   // expandO(pair 1): row 3
            Ob = (double)(rlane(blvc, 3) + EPSF);
            Oa = (double)(sl[1][1] + EPSF);
            Oc = (double)(sl[1][3] + EPSF);
        }

        // chunk 0: pairs 1..15 (rows 2..31)
        {
            const float* rb  = bufs[0];
            const float* rbn = bufs[1];
            #pragma unroll
            for (int qi = 1; qi < 16; ++qi) {
                const int rr = 2 * qi;
                const float* nxt = (rr + 6 < CHUNK) ? (rb + (rr + 6) * Cc)
                                                    : (rbn + (rr + 6 - CHUNK) * Cc);
                gpair(nxt, sl[(qi + 3) & 3]);
                stepE();
                {   // expandE(pair qi+1): row rr+2 (next chunk row 0 at qi=15)
                    const float* s = sl[(qi + 1) & 3];
                    const float bz = (qi < 15) ? rlane(blvc, rr + 2)
                                               : rlane(blvn, 0);
                    Eb = (double)(bz + EPSF);
                    Ea = (double)(s[0] + EPSF);
                    Ec = (double)(s[2] + EPSF);
                }
                stepO();
                {   // expandO(pair qi+1): row rr+3
                    const float* s = sl[(qi + 1) & 3];
                    const float bz = (qi < 15) ? rlane(blvc, rr + 3)
                                               : rlane(blvn, 1);
                    Ob = (double)(bz + EPSF);
                    Oa = (double)(s[1] + EPSF);
                    Oc = (double)(s[3] + EPSF);
                }
            }
        }
        // chunks 1..15 (rows 32..511)
        for (int k = 1; k < 16; ++k) {
            syncex(k + 2);
            blvc = blvn;
            if (k < 15) blvn = loadblv(k + 1);
            const float* rb  = bufs[k % 3];
            const float* rbn = bufs[(k + 1) % 3];    // k=15: dead reads, safe
            #pragma unroll
            for (int qi = 0; qi < 16; ++qi) {
                const int rr = 2 * qi;
                const float* nxt = (rr + 6 < CHUNK) ? (rb + (rr + 6) * Cc)
                                                    : (rbn + (rr + 6 - CHUNK) * Cc);
                gpair(nxt, sl[(qi + 3) & 3]);
                stepE();
                {
                    const float* s = sl[(qi + 1) & 3];
                    const float bz = (qi < 15) ? rlane(blvc, rr + 2)
                                               : rlane(blvn, 0);
                    Eb = (double)(bz + EPSF);
                    Ea = (double)(s[0] + EPSF);
                    Ec = (double)(s[2] + EPSF);
                }
                stepO();
                {
                    const float* s = sl[(qi + 1) & 3];
                    const float bz = (qi < 15) ? rlane(blvc, rr + 3)
                                               : rlane(blvn, 1);
                    Ob = (double)(bz + EPSF);
                    Oa = (double)(s[1] + EPSF);
                    Oc = (double)(s[3] + EPSF);
                }
            }
        }
        // publish alpha_511 (pre-rescale) + toteF
        if (ow0) wsb[s0]     = a0;
        if (ow1) wsb[s0 + 1] = a1;
        if (ow2) wsb[s0 + 2] = a2;
        if (ow3) wsb[s0 + 3] = a3;
        if (tid == 0) wsb[513] = (double)tote;
    } else {
        // =================== BACKWARD: rows 1023 .. 512 ===================
        double b0 = 0, b1 = 0, b2 = 0, b3 = 0, n0 = 0, n1 = 0;
        int tote = 0;
        double Eb, Ea, Ec, Ed, Ob, Oa, Oc, Od;
        float blvc, blvn;

        auto stepBE = [&]() {
            const double x1 = Ea * b1, x2 = Eb * b2, x3 = Ec * b3, z = Ed * n1;
            const double r0 = __fma_rn(Eb, b0, x1);
            const double r1 = __fma_rn(sm_b, x3, x1 + x2);
            const double r2 = x2 + x3;
            const double r3 = __fma_rn(sm_c, z, __fma_rn(Eb, n0, x3));
            b0 = r0; b1 = r1; b2 = r2; b3 = r3;
            n0 = dpp_wave_shl1_f64(b0);
            n1 = dpp_wave_shl1_f64(b1);
        };
        auto stepBO = [&]() {
            const double x1 = Oa * b1, x2 = Ob * b2, x3 = Oc * b3, z = Od * n1;
            const double r0 = __fma_rn(Ob, b0, x1);
            const double r1 = __fma_rn(sm_b, x3, x1 + x2);
            const double r2 = x2 + x3;
            const double r3 = __fma_rn(sm_c, z, __fma_rn(Ob, n0, x3));
            b0 = r0; b1 = r1; b2 = r2; b3 = r3;
            n0 = dpp_wave_shl1_f64(b0);
            n1 = dpp_wave_shl1_f64(b1);
        };
        auto syncex = [&](int sk) {
            int e =        om0 & (__double2hiint(b0) >> 20);
            e = max(e, om1 & (__double2hiint(b1) >> 20));
            e = max(e, om2 & (__double2hiint(b2) >> 20));
            e = max(e, om3 & (__double2hiint(b3) >> 20));
            e = DPPMAXI(e, 0x111); e = DPPMAXI(e, 0x112);
            e = DPPMAXI(e, 0x114); e = DPPMAXI(e, 0x118);
            e = DPPMAXI(e, 0x142); e = DPPMAXI(e, 0x143);
            if (lane == 63) em[wl] = e;
            if (ow0) ash[s0]     = b0;
            if (ow1) ash[s0 + 1] = b1;
            if (ow2) ash[s0 + 2] = b2;
            if (ow3) ash[s0 + 3] = b3;
            __syncthreads();               // barrier 1
            const int eg = max(max(em[0], em[1]), max(em[2], em[3]));
            const int sexp = min(max(2046 - eg, 1), 2045);
            const double sc = __hiloint2double(sexp << 20, 0);
            tote += 1023 - sexp;
            // refresh pad above from owner; zero beyond S space
            if (s0     >= own_e) b0 = (s0     < Sc) ? ash[s0]     : 0.0;
            if (s0 + 1 >= own_e) b1 = (s0 + 1 < Sc) ? ash[s0 + 1] : 0.0;
            if (s0 + 2 >= own_e) b2 = (s0 + 2 < Sc) ? ash[s0 + 2] : 0.0;
            if (s0 + 3 >= own_e) b3 = (s0 + 3 < Sc) ? ash[s0 + 3] : 0.0;
            b0 *= sc; b1 *= sc; b2 *= sc; b3 *= sc;
            n0 = dpp_wave_shl1_f64(b0);
            n1 = dpp_wave_shl1_f64(b1);
            __syncthreads();               // barrier 2
            if (sk >= 16) stage(sk, bufs[(31 - sk) % 3]);
        };

        // ---- prologue: chunks 31,30,29 -> bufs 0,1,2 ----
        stage(31, bufs[0]); stage(30, bufs[1]); stage(29, bufs[2]);
        blvc = loadblv(31);
        blvn = loadblv(30);
        __syncthreads();

        // init beta_{1023}: 1 at end states {2L, 2L-1}
        {
            const int e0 = 2 * lab_len;
            const int e1 = (lab_len > 0) ? (2 * lab_len - 1) : e0;
            b0 = (s0     == e0 || s0     == e1) ? 1.0 : 0.0;
            b1 = (s0 + 1 == e0 || s0 + 1 == e1) ? 1.0 : 0.0;
            b2 = (s0 + 2 == e0 || s0 + 2 == e1) ? 1.0 : 0.0;
            b3 = (s0 + 3 == e0 || s0 + 3 == e1) ? 1.0 : 0.0;
            n0 = dpp_wave_shl1_f64(b0);
            n1 = dpp_wave_shl1_f64(b1);
        }
        // prime pairs 15,14,13 -> slots 3,2,1
        gpair(bufs[0] + 30 * Cc, sl[3]);
        gpair(bufs[0] + 28 * Cc, sl[2]);
        gpair(bufs[0] + 26 * Cc, sl[1]);
        {   // expandOB(pair 15): row 31
            Ob = (double)(rlane(blvc, 31) + EPSF);
            Oa = (double)(sl[3][1] + EPSF);
            Oc = (double)(sl[3][3] + EPSF);
            Od = (double)(dpp_wave_shl1_f32(sl[3][1]) + EPSF);
        }
        {   // expandEB(pair 15): row 30
            Eb = (double)(rlane(blvc, 30) + EPSF);
            Ea = (double)(sl[3][0] + EPSF);
            Ec = (double)(sl[3][2] + EPSF);
            Ed = (double)(dpp_wave_shl1_f32(sl[3][0]) + EPSF);
        }

        // chunk 31: q = 15..0 (rows descend; odd step first per pair)
        {
            const float* rb  = bufs[0];
            const float* rbn = bufs[1];    // chunk 30
            #pragma unroll
            for (int j = 0; j < 16; ++j) {
                const int q = 15 - j;
                const int rr = 2 * q;
                const float* nxt = (rr - 6 >= 0) ? (rb + (rr - 6) * Cc)
                                                 : (rbn + (rr - 6 + CHUNK) * Cc);
                gpair(nxt, sl[(q + 1) & 3]);   // pair q-3
                stepBO();
                {   // expandOB(pair q-1): row rr-1 (prev-chunk row 31 at q=0)
                    const float* s = sl[(q - 1) & 3];
                    const float bz = (q > 0) ? rlane(blvc, rr - 1)
                                             : rlane(blvn, 31);
                    Ob = (double)(bz + EPSF);
                    Oa = (double)(s[1] + EPSF);
                    Oc = (double)(s[3] + EPSF);
                    Od = (double)(dpp_wave_shl1_f32(s[1]) + EPSF);
                }
                stepBE();
                {   // expandEB(pair q-1): row rr-2
                    const float* s = sl[(q - 1) & 3];
                    const float bz = (q > 0) ? rlane(blvc, rr - 2)
                                             : rlane(blvn, 30);
                    Eb = (double)(bz + EPSF);
                    Ea = (double)(s[0] + EPSF);
                    Ec = (double)(s[2] + EPSF);
                    Ed = (double)(dpp_wave_shl1_f32(s[0]) + EPSF);
                }
            }
        }
        // chunks 30..16
        for (int c = 30; c >= 16; --c) {
            syncex(c - 2);
            blvc = blvn;
            if (c > 16) blvn = loadblv(c - 1);
            const float* rb  = bufs[(31 - c) % 3];
            const float* rbn = bufs[(32 - c) % 3];   // c=16: dead reads, safe
            #pragma unroll
            for (int j = 0; j < 16; ++j) {
                const int q = 15 - j;
                const int rr = 2 * q;
                const float* nxt = (rr - 6 >= 0) ? (rb + (rr - 6) * Cc)
                                                 : (rbn + (rr - 6 + CHUNK) * Cc);
                gpair(nxt, sl[(q + 1) & 3]);
                stepBO();
                {
                    const float* s = sl[(q - 1) & 3];
                    const float bz = (q > 0) ? rlane(blvc, rr - 1)
                                             : rlane(blvn, 31);
                    Ob = (double)(bz + EPSF);
                    Oa = (double)(s[1] + EPSF);
                    Oc = (double)(s[3] + EPSF);
                    Od = (double)(dpp_wave_shl1_f32(s[1]) + EPSF);
                }
                stepBE();
                {
                    const float* s = sl[(q - 1) & 3];
                    const float bz = (q > 0) ? rlane(blvc, rr - 2)
                                             : rlane(blvn, 30);
                    Eb = (double)(bz + EPSF);
                    Ea = (double)(s[0] + EPSF);
                    Ec = (double)(s[2] + EPSF);
                    Ed = (double)(dpp_wave_shl1_f32(s[0]) + EPSF);
                }
            }
        }
        // publish beta_511 (pre-rescale) + toteB
        if (ow0) wsb[514 + s0]     = b0;
        if (ow1) wsb[514 + s0 + 1] = b1;
        if (ow2) wsb[514 + s0 + 2] = b2;
        if (ow3) wsb[514 + s0 + 3] = b3;
        if (tid == 0) wsb[1027] = (double)tote;
    }

    // ---- folded combine: last finisher for batch b does dot + log ----
    __threadfence();                       // release our ws writes
    if (tid == 0) {
        int* flags = (int*)(ws + FLAGS_OFF);
        amlast = (atomicAdd(&flags[b], 1) == 1);
    }
    __syncthreads();
    if (amlast && tid < 64) {
        __threadfence();                   // acquire other block's writes
        const double* wf = ws + (size_t)b * WSSTRIDE;
        const double* wb = wf + 514;
        int eP = 0;                        // max biased-exponent product sum
        for (int s = tid; s < S2; s += 64) {
            const int ea = (__double2hiint(wf[s]) >> 20) & 0x7ff;
            const int eb2 = (__double2hiint(wb[s]) >> 20) & 0x7ff;
            if (ea && eb2) eP = max(eP, ea + eb2);
        }
        #pragma unroll
        for (int m = 1; m < 64; m <<= 1) eP = max(eP, __shfl_xor(eP, m));
        const int sh = 2046 - eP;
        int k1 = sh / 2;
        int k2 = sh - k1;
        k1 = min(max(k1, -1022), 1023);
        k2 = min(max(k2, -1022), 1023);
        const double scA = __hiloint2double((1023 + k1) << 20, 0);
        const double scB = __hiloint2double((1023 + k2) << 20, 0);
        double dot = 0.0;
        for (int s = tid; s < S2; s += 64)
            dot += (wf[s] * scA) * (wb[s] * scB);
        #pragma unroll
        for (int m = 1; m < 64; m <<= 1) dot += __shfl_xor(dot, m);
        if (tid == 0) {
            const double lt = wf[513] + wb[513] - (double)k1 - (double)k2;
            out[b] = (float)(-(log(dot) + lt * 0.6931471805599453));
        }
    }
}

extern "C" void kernel_launch(void* const* d_in, const int* in_sizes, int n_in,
                              void* d_out, int out_size, void* d_ws, size_t ws_size,
                              hipStream_t stream) {
    const int*   y_true       = (const int*)d_in[0];
    const float* y_pred       = (const float*)d_in[1];
    const int*   label_length = (const int*)d_in[3];
    float* out = (float*)d_out;
    double* ws = (double*)d_ws;

    hipMemsetAsync((char*)d_ws + FLAGS_OFF * sizeof(double), 0,
                   Bc * sizeof(int), stream);
    ctc_fb_kernel<<<2 * Bc, NW * 64, 0, stream>>>(y_true, y_pred,
                                                  label_length, ws, out);
}

// Round 12
// 115.834 us; speedup vs baseline: 1.1590x; 1.1076x over previous
//
#include <hip/hip_runtime.h>

// CTC loss forward, f64 prob-domain with power-of-2 rescaling.
// v13: EXACT v5 revert (best measured: 45.5us kernel / 117.2us harness)
// + single-barrier syncex via double-buffered exchange arrays.
// Delivery-restructure scorecard v6-v12: 0/7 (8-wave LDS contention, load
// sinking, VGPR spills x3, slot collapse, readlane serialization). v5's
// 3-slot LDS gather pipeline is the compiler's sharp local optimum -- left
// byte-identical here. The one provably-redundant structure: syncex barrier
// #2 only protected ash/em reuse; with ash[2]/em[2] alternating per chunk,
// the next same-buffer write is two syncex calls away, separated by the
// intervening barrier #1 (each wave's pad-refresh reads complete before it
// reaches that barrier -> no race). Deletes 16 barriers + implicit full
// vmcnt/lgkm drains per block. No FP changes -> absmax must stay 0.0.
// ws layout per b (doubles, stride 1028): [0..512] alphaF, [513] toteF,
// [514..1026] betaB, [1027] toteB.

#define Bc 64
#define Tc 1024
#define Cc 128
#define Lc 256
#define Sc 513
#define BLANKc 127
#define CHUNK 32
#define NW 4
#define PADS 64
#define WSSTRIDE 1028

constexpr float EPSF = 1e-7f;

#define DPPMAXI(x, ctrl) max(x, __builtin_amdgcn_update_dpp( \
    0, x, ctrl, 0xf, 0xf, true))

__device__ __forceinline__ double dpp_wave_shr1_f64(double x) {
    // lane l <- lane l-1; lane 0 <- 0 (bound_ctrl)
    union { double d; int i[2]; } u, r;
    u.d = x;
    r.i[0] = __builtin_amdgcn_update_dpp(0, u.i[0], 0x138, 0xf, 0xf, true);
    r.i[1] = __builtin_amdgcn_update_dpp(0, u.i[1], 0x138, 0xf, 0xf, true);
    return r.d;
}
__device__ __forceinline__ double dpp_wave_shl1_f64(double x) {
    // lane l <- lane l+1; lane 63 <- 0 (bound_ctrl)
    union { double d; int i[2]; } u, r;
    u.d = x;
    r.i[0] = __builtin_amdgcn_update_dpp(0, u.i[0], 0x130, 0xf, 0xf, true);
    r.i[1] = __builtin_amdgcn_update_dpp(0, u.i[1], 0x130, 0xf, 0xf, true);
    return r.d;
}

__global__ __launch_bounds__(256, 1) void ctc_fb_kernel(
    const int* __restrict__ y_true,        // [B, L]
    const float* __restrict__ y_pred,      // [B, T, C]
    const int* __restrict__ label_length,  // [B, 1]
    double* __restrict__ ws)
{
    const int bb = blockIdx.x;
    const int b = bb >> 1;
    const bool isF = !(bb & 1);
    const int tid = (int)threadIdx.x;
    const int wl = tid >> 6;               // wave 0..3
    const int lane = tid & 63;

    __shared__ float bufs[3][CHUNK * Cc];  // 3 x 16 KB staged y_pred rows
    __shared__ double ash[2][Sc];          // DOUBLE-BUFFERED exchange
    __shared__ int em[2][NW];              // DOUBLE-BUFFERED exponent max

    const int lab_len = label_length[b];
    const float* yp = y_pred + (size_t)b * Tc * Cc;
    const int* lab = y_true + b * Lc;
    double* wsb = ws + (size_t)b * WSSTRIDE;

    // ---- region geometry (starts EVEN). fwd pads BELOW owned, bwd ABOVE.
    const int start = isF ? ((wl == 0) ? 0 : (128 * wl - PADS)) : (128 * wl);
    const int own_s = 128 * wl;
    const int own_e = (wl == NW - 1) ? Sc : (128 * (wl + 1));
    const int s0 = start + 4 * lane;       // even; lane holds s0..s0+3

    // ---- per-lane static metadata ----
    const int li0 = s0 >> 1;               // label idx of state s0+1
    const int li0c = min(li0, Lc - 1);
    const int li1c = min(li0 + 1, Lc - 1);
    const int li2c = min(li0 + 2, Lc - 1);
    const int ca = lab[li0c], cb = lab[li1c], cc = lab[li2c];
    const double sm_a = (li0 > 0 && ca != BLANKc && ca != lab[li0c - 1]) ? 1.0 : 0.0;
    const double sm_b = (cb != BLANKc && cb != ca) ? 1.0 : 0.0;
    const double sm_c = (cc != BLANKc && cc != cb) ? 1.0 : 0.0;

    const int S2 = 2 * lab_len + 1;
    const bool ow0 = (s0     >= own_s) && (s0     < own_e);
    const bool ow1 = (s0 + 1 >= own_s) && (s0 + 1 < own_e);
    const bool ow2 = (s0 + 2 >= own_s) && (s0 + 2 < own_e);
    const bool ow3 = (s0 + 3 >= own_s) && (s0 + 3 < own_e);
    const int om0 = (ow0 && s0     < S2) ? -1 : 0;
    const int om1 = (ow1 && s0 + 1 < S2) ? -1 : 0;
    const int om2 = (ow2 && s0 + 2 < S2) ? -1 : 0;
    const int om3 = (ow3 && s0 + 3 < S2) ? -1 : 0;

    // ---- staging: each wave DMAs its quarter (4 KB) of a 16 KB chunk ----
    auto stage = [&](int c, float* dst) {
        const float* g = yp + (size_t)c * (CHUNK * Cc) + lane * 4;
        #pragma unroll
        for (int q = 0; q < 4; ++q) {
            const int i = wl * 4 + q;
            __builtin_amdgcn_global_load_lds(
                (const __attribute__((address_space(1))) void*)(g + i * 256),
                (__attribute__((address_space(3))) void*)(dst + i * 256),
                16, 0, 0);
        }
    };

    if (isF) {
        // =================== FORWARD: rows 0 .. 511 ===================
        double a0 = 0, a1 = 0, a2 = 0, a3 = 0, n3 = 0;
        int tote = 0;
        double Eb, Ea, Ec;                 // even-row p: blank, ca, cb
        double Ob, Oa, Oc;                 // odd-row p
        float sl[4][6];                    // pair P in sl[P&3], gathered 3 ahead

        auto gpair = [&](const float* rowp, float* s) {
            s[0] = rowp[BLANKc]; s[1] = rowp[BLANKc + Cc];
            s[2] = rowp[ca];     s[3] = rowp[ca + Cc];
            s[4] = rowp[cb];     s[5] = rowp[cb + Cc];
        };
        auto expandE = [&](const float* s) {
            Eb = (double)(s[0] + EPSF); Ea = (double)(s[2] + EPSF);
            Ec = (double)(s[4] + EPSF);
        };
        auto expandO = [&](const float* s) {
            Ob = (double)(s[1] + EPSF); Oa = (double)(s[3] + EPSF);
            Oc = (double)(s[5] + EPSF);
        };
        auto stepE = [&]() {
            const double t3 = __fma_rn(sm_b, a1, a3 + a2);
            const double t2 = a2 + a1;
            const double t1 = __fma_rn(sm_a, n3, a1 + a0);
            const double t0 = a0 + n3;
            a3 = t3 * Ec;
            n3 = dpp_wave_shr1_f64(a3);
            a2 = t2 * Eb; a1 = t1 * Ea; a0 = t0 * Eb;
        };
        auto stepO = [&]() {
            const double t3 = __fma_rn(sm_b, a1, a3 + a2);
            const double t2 = a2 + a1;
            const double t1 = __fma_rn(sm_a, n3, a1 + a0);
            const double t0 = a0 + n3;
            a3 = t3 * Oc;
            n3 = dpp_wave_shr1_f64(a3);
            a2 = t2 * Ob; a1 = t1 * Oa; a0 = t0 * Ob;
        };
        auto syncex = [&](int sk, int p) {
            int e =        om0 & (__double2hiint(a0) >> 20);
            e = max(e, om1 & (__double2hiint(a1) >> 20));
            e = max(e, om2 & (__double2hiint(a2) >> 20));
            e = max(e, om3 & (__double2hiint(a3) >> 20));
            e = DPPMAXI(e, 0x111); e = DPPMAXI(e, 0x112);
            e = DPPMAXI(e, 0x114); e = DPPMAXI(e, 0x118);
            e = DPPMAXI(e, 0x142); e = DPPMAXI(e, 0x143);
            if (lane == 63) em[p][wl] = e;
            if (ow0) ash[p][s0]     = a0;
            if (ow1) ash[p][s0 + 1] = a1;
            if (ow2) ash[p][s0 + 2] = a2;
            if (ow3) ash[p][s0 + 3] = a3;
            __syncthreads();               // the ONLY barrier per chunk
            const int eg = max(max(em[p][0], em[p][1]),
                               max(em[p][2], em[p][3]));
            const int sexp = min(max(2046 - eg, 1), 2045);
            const double sc = __hiloint2double(sexp << 20, 0);
            tote += 1023 - sexp;
            if (wl > 0 && lane < (PADS / 4)) {   // refresh pad from below-owner
                a0 = ash[p][s0];     a1 = ash[p][s0 + 1];
                a2 = ash[p][s0 + 2]; a3 = ash[p][s0 + 3];
            }
            a0 *= sc; a1 *= sc; a2 *= sc; a3 *= sc;
            n3 = dpp_wave_shr1_f64(a3);
            // no barrier 2: next write to ash[p]/em[p] is 2 syncex away,
            // separated by the intervening syncex's barrier.
            if (sk <= 15) stage(sk, bufs[sk % 3]);  // DMA after exchange
        };

        // ---- prologue ----
        stage(0, bufs[0]); stage(1, bufs[1]); stage(2, bufs[2]);
        __syncthreads();

        if (wl == 0 && lane == 0) {
            a0 = (double)(bufs[0][BLANKc] + EPSF);               // s=0
            if (lab_len > 0) a1 = (double)(bufs[0][ca] + EPSF);  // s=1
        }
        gpair(bufs[0] + 2 * Cc, sl[1]);
        gpair(bufs[0] + 4 * Cc, sl[2]);
        gpair(bufs[0] + 6 * Cc, sl[3]);
        {
            const float* r1 = bufs[0] + 1 * Cc;
            Ob = (double)(r1[BLANKc] + EPSF);
            Oa = (double)(r1[ca] + EPSF);
            Oc = (double)(r1[cb] + EPSF);
        }
        expandE(sl[1]);                    // row 2

        stepO();                           // lone step t=1
        expandO(sl[1]);                    // row 3

        // chunk 0: pairs 1..15 (rows 2..31)
        {
            const float* rb  = bufs[0];
            const float* rbn = bufs[1];
            #pragma unroll
            for (int qi = 1; qi < 16; ++qi) {
                const int rr = 2 * qi;
                const float* nxt = (rr + 6 < CHUNK) ? (rb + (rr + 6) * Cc)
                                                    : (rbn + (rr + 6 - CHUNK) * Cc);
                gpair(nxt, sl[(qi + 3) & 3]);
                stepE();
                expandE(sl[(qi + 1) & 3]);
                stepO();
                expandO(sl[(qi + 1) & 3]);
            }
        }
        // chunks 1..15 (rows 32..511)
        for (int k = 1; k < 16; ++k) {
            syncex(k + 2, k & 1);
            const float* rb  = bufs[k % 3];
            const float* rbn = bufs[(k + 1) % 3];   // k=15: dead reads, safe
            #pragma unroll
            for (int qi = 0; qi < 16; ++qi) {
                const int rr = 2 * qi;
                const float* nxt = (rr + 6 < CHUNK) ? (rb + (rr + 6) * Cc)
                                                    : (rbn + (rr + 6 - CHUNK) * Cc);
                gpair(nxt, sl[(qi + 3) & 3]);
                stepE();
                expandE(sl[(qi + 1) & 3]);
                stepO();
                expandO(sl[(qi + 1) & 3]);
            }
        }
        // publish alpha_511 (pre-rescale) + toteF
        if (ow0) wsb[s0]     = a0;
        if (ow1) wsb[s0 + 1] = a1;
        if (ow2) wsb[s0 + 2] = a2;
        if (ow3) wsb[s0 + 3] = a3;
        if (tid == 0) wsb[513] = (double)tote;
    } else {
        // =================== BACKWARD: rows 1023 .. 512 ===================
        // beta'(s) = sum_{s' in {s, s+1, s+2*sk(s+2)}} p_t(s') * beta(s')
        double b0 = 0, b1 = 0, b2 = 0, b3 = 0, n0 = 0, n1 = 0;
        int tote = 0;
        double Eb, Ea, Ec, Ed;             // even-row p: blank, ca, cb, cc
        double Ob, Oa, Oc, Od;             // odd-row p
        float sl[4][8];

        auto gpair = [&](const float* rowp, float* s) {
            s[0] = rowp[BLANKc]; s[1] = rowp[BLANKc + Cc];
            s[2] = rowp[ca];     s[3] = rowp[ca + Cc];
            s[4] = rowp[cb];     s[5] = rowp[cb + Cc];
            s[6] = rowp[cc];     s[7] = rowp[cc + Cc];
        };
        auto expandE = [&](const float* s) {
            Eb = (double)(s[0] + EPSF); Ea = (double)(s[2] + EPSF);
            Ec = (double)(s[4] + EPSF); Ed = (double)(s[6] + EPSF);
        };
        auto expandO = [&](const float* s) {
            Ob = (double)(s[1] + EPSF); Oa = (double)(s[3] + EPSF);
            Oc = (double)(s[5] + EPSF); Od = (double)(s[7] + EPSF);
        };
        auto stepBE = [&]() {
            const double x1 = Ea * b1, x2 = Eb * b2, x3 = Ec * b3, z = Ed * n1;
            const double r0 = __fma_rn(Eb, b0, x1);
            const double r1 = __fma_rn(sm_b, x3, x1 + x2);
            const double r2 = x2 + x3;
            const double r3 = __fma_rn(sm_c, z, __fma_rn(Eb, n0, x3));
            b0 = r0; b1 = r1; b2 = r2; b3 = r3;
            n0 = dpp_wave_shl1_f64(b0);
            n1 = dpp_wave_shl1_f64(b1);
        };
        auto stepBO = [&]() {
            const double x1 = Oa * b1, x2 = Ob * b2, x3 = Oc * b3, z = Od * n1;
            const double r0 = __fma_rn(Ob, b0, x1);
            const double r1 = __fma_rn(sm_b, x3, x1 + x2);
            const double r2 = x2 + x3;
            const double r3 = __fma_rn(sm_c, z, __fma_rn(Ob, n0, x3));
            b0 = r0; b1 = r1; b2 = r2; b3 = r3;
            n0 = dpp_wave_shl1_f64(b0);
            n1 = dpp_wave_shl1_f64(b1);
        };
        auto syncex = [&](int sk, int p) {
            int e =        om0 & (__double2hiint(b0) >> 20);
            e = max(e, om1 & (__double2hiint(b1) >> 20));
            e = max(e, om2 & (__double2hiint(b2) >> 20));
            e = max(e, om3 & (__double2hiint(b3) >> 20));
            e = DPPMAXI(e, 0x111); e = DPPMAXI(e, 0x112);
            e = DPPMAXI(e, 0x114); e = DPPMAXI(e, 0x118);
            e = DPPMAXI(e, 0x142); e = DPPMAXI(e, 0x143);
            if (lane == 63) em[p][wl] = e;
            if (ow0) ash[p][s0]     = b0;
            if (ow1) ash[p][s0 + 1] = b1;
            if (ow2) ash[p][s0 + 2] = b2;
            if (ow3) ash[p][s0 + 3] = b3;
            __syncthreads();               // the ONLY barrier per chunk
            const int eg = max(max(em[p][0], em[p][1]),
                               max(em[p][2], em[p][3]));
            const int sexp = min(max(2046 - eg, 1), 2045);
            const double sc = __hiloint2double(sexp << 20, 0);
            tote += 1023 - sexp;
            // refresh pad above from owner; zero beyond S space
            if (s0     >= own_e) b0 = (s0     < Sc) ? ash[p][s0]     : 0.0;
            if (s0 + 1 >= own_e) b1 = (s0 + 1 < Sc) ? ash[p][s0 + 1] : 0.0;
            if (s0 + 2 >= own_e) b2 = (s0 + 2 < Sc) ? ash[p][s0 + 2] : 0.0;
            if (s0 + 3 >= own_e) b3 = (s0 + 3 < Sc) ? ash[p][s0 + 3] : 0.0;
            b0 *= sc; b1 *= sc; b2 *= sc; b3 *= sc;
            n0 = dpp_wave_shl1_f64(b0);
            n1 = dpp_wave_shl1_f64(b1);
            if (sk >= 16) stage(sk, bufs[(31 - sk) % 3]);
        };

        // ---- prologue: chunks 31,30,29 -> bufs 0,1,2 ----
        stage(31, bufs[0]); stage(30, bufs[1]); stage(29, bufs[2]);
        __syncthreads();

        // init beta_{1023}: 1 at end states {2L, 2L-1}
        {
            const int e0 = 2 * lab_len;
            const int e1 = (lab_len > 0) ? (2 * lab_len - 1) : e0;
            b0 = (s0     == e0 || s0     == e1) ? 1.0 : 0.0;
            b1 = (s0 + 1 == e0 || s0 + 1 == e1) ? 1.0 : 0.0;
            b2 = (s0 + 2 == e0 || s0 + 2 == e1) ? 1.0 : 0.0;
            b3 = (s0 + 3 == e0 || s0 + 3 == e1) ? 1.0 : 0.0;
            n0 = dpp_wave_shl1_f64(b0);
            n1 = dpp_wave_shl1_f64(b1);
        }
        // prime chunk 31 (bufs[0]): pairs 15,14,13 -> slots 3,2,1
        gpair(bufs[0] + 30 * Cc, sl[3]);
        gpair(bufs[0] + 28 * Cc, sl[2]);
        gpair(bufs[0] + 26 * Cc, sl[1]);
        expandO(sl[3]);                    // row 31 (abs t=1023)
        expandE(sl[3]);                    // row 30

        // chunk 31: q = 15..0 (rows descend; odd step first per pair)
        {
            const float* rb  = bufs[0];
            const float* rbn = bufs[1];    // chunk 30
            #pragma unroll
            for (int j = 0; j < 16; ++j) {
                const int q = 15 - j;
                const int rr = 2 * q;
                const float* nxt = (rr - 6 >= 0) ? (rb + (rr - 6) * Cc)
                                                 : (rbn + (rr - 6 + CHUNK) * Cc);
                gpair(nxt, sl[(q + 1) & 3]);   // pair q-3 (3 ahead in order)
                stepBO();
                expandO(sl[(q - 1) & 3]);
                stepBE();
                expandE(sl[(q - 1) & 3]);
            }
        }
        // chunks 30..16
        for (int c = 30; c >= 16; --c) {
            syncex(c - 2, c & 1);
            const float* rb  = bufs[(31 - c) % 3];
            const float* rbn = bufs[(32 - c) % 3];  // c=16: dead reads, safe
            #pragma unroll
            for (int j = 0; j < 16; ++j) {
                const int q = 15 - j;
                const int rr = 2 * q;
                const float* nxt = (rr - 6 >= 0) ? (rb + (rr - 6) * Cc)
                                                 : (rbn + (rr - 6 + CHUNK) * Cc);
                gpair(nxt, sl[(q + 1) & 3]);
                stepBO();
                expandO(sl[(q - 1) & 3]);
                stepBE();
                expandE(sl[(q - 1) & 3]);
            }
        }
        // publish beta_511 (pre-rescale) + toteB
        if (ow0) wsb[514 + s0]     = b0;
        if (ow1) wsb[514 + s0 + 1] = b1;
        if (ow2) wsb[514 + s0 + 2] = b2;
        if (ow3) wsb[514 + s0 + 3] = b3;
        if (tid == 0) wsb[1027] = (double)tote;
    }
}

__global__ __launch_bounds__(64) void ctc_combine(
    const int* __restrict__ label_length,
    const double* __restrict__ ws,
    float* __restrict__ out)
{
    const int b = blockIdx.x;
    const int lane = (int)threadIdx.x;
    const int lab_len = label_length[b];
    const int S2 = 2 * lab_len + 1;
    const double* wf = ws + (size_t)b * WSSTRIDE;
    const double* wb = wf + 514;

    int eP = 0;                            // max biased-exponent sum of products
    for (int s = lane; s < S2; s += 64) {
        const int ea = (__double2hiint(wf[s]) >> 20) & 0x7ff;
        const int eb = (__double2hiint(wb[s]) >> 20) & 0x7ff;
        if (ea && eb) eP = max(eP, ea + eb);
    }
    #pragma unroll
    for (int m = 1; m < 64; m <<= 1) eP = max(eP, __shfl_xor(eP, m));
    const int sh = 2046 - eP;
    int k1 = sh / 2;
    int k2 = sh - k1;
    k1 = min(max(k1, -1022), 1023);
    k2 = min(max(k2, -1022), 1023);
    const double scA = __hiloint2double((1023 + k1) << 20, 0);
    const double scB = __hiloint2double((1023 + k2) << 20, 0);
    double dot = 0.0;
    for (int s = lane; s < S2; s += 64)
        dot += (wf[s] * scA) * (wb[s] * scB);
    #pragma unroll
    for (int m = 1; m < 64; m <<= 1) dot += __shfl_xor(dot, m);
    if (lane == 0) {
        const double lt = wf[513] + wb[513] - (double)k1 - (double)k2;
        out[b] = (float)(-(log(dot) + lt * 0.6931471805599453));
    }
}

extern "C" void kernel_launch(void* const* d_in, const int* in_sizes, int n_in,
                              void* d_out, int out_size, void* d_ws, size_t ws_size,
                              hipStream_t stream) {
    const int*   y_true       = (const int*)d_in[0];
    const float* y_pred       = (const float*)d_in[1];
    const int*   label_length = (const int*)d_in[3];
    float* out = (float*)d_out;
    double* ws = (double*)d_ws;

    ctc_fb_kernel<<<2 * Bc, NW * 64, 0, stream>>>(y_true, y_pred,
                                                  label_length, ws);
    ctc_combine<<<Bc, 64, 0, stream>>>(label_length, ws, out);
}